// Round 1
// baseline (601.732 us; speedup 1.0000x reference)
//
#include <hip/hip_runtime.h>

// RunningCenters: per-class mean of x[N,D] by labels y, then CMA update of
// centers[C,D]. Memory-bound: x = 256 MB read-once dominates.
//
// Strategy: LDS-privatized scatter-add. Grid = (point-tiles P) x (dim-slices).
// Each block owns a [C x SLICE] f32 LDS accumulator (padded stride to spread
// banks), streams its point-range/dim-slice of x with ds_add_f32 (via
// unsafeAtomicAdd -> native LDS float atomic), then flushes with PLAIN stores
// to a per-tile partial buffer (disjoint regions -> no global atomics, no
// pre-zero needed). A final kernel reduces the P partials and applies the CMA.

constexpr int C = 1000;
constexpr int D = 128;
constexpr int SLICE = 16;               // dims per slice
constexpr int NSLICES = D / SLICE;      // 8
constexpr int LPAD = 17;                // padded LDS stride (bank spread)
constexpr int TPB1 = 512;               // 8 waves/block
constexpr int PPI = TPB1 / SLICE;       // 32 points per iteration

__global__ __launch_bounds__(256) void counts_kernel(
    const int* __restrict__ y, unsigned int* __restrict__ counts, int N) {
  __shared__ unsigned int h[C];
  for (int t = threadIdx.x; t < C; t += 256) h[t] = 0u;
  __syncthreads();
  for (int i = blockIdx.x * 256 + threadIdx.x; i < N; i += gridDim.x * 256)
    atomicAdd(&h[y[i]], 1u);
  __syncthreads();
  for (int t = threadIdx.x; t < C; t += 256) {
    unsigned int v = h[t];
    if (v) atomicAdd(&counts[t], v);
  }
}

// block (p, s): points [p*chunk, (p+1)*chunk) x dims [s*SLICE, (s+1)*SLICE)
__global__ __launch_bounds__(TPB1, 2) void partial_sums_kernel(
    const float* __restrict__ x, const int* __restrict__ y,
    float* __restrict__ partial, int N, int chunk) {
  __shared__ float lsum[C * LPAD];  // 68 KB -> 2 blocks/CU (160 KB LDS)
  const int p = blockIdx.x;
  const int s = blockIdx.y;
  for (int i = threadIdx.x; i < C * LPAD; i += TPB1) lsum[i] = 0.f;
  __syncthreads();

  const int dim  = threadIdx.x & (SLICE - 1);
  const int psub = threadIdx.x >> 4;  // threadIdx.x / SLICE
  int begin = p * chunk;
  int end = begin + chunk;
  if (end > N) end = N;

  const float* xc = x + s * SLICE + dim;  // column pointer for this thread
  int i = begin + psub;
  // unroll x4: 4 independent loads in flight per thread (~1 KB/wave)
  for (; i + 3 * PPI < end; i += 4 * PPI) {
    int c0 = y[i];
    int c1 = y[i + PPI];
    int c2 = y[i + 2 * PPI];
    int c3 = y[i + 3 * PPI];
    float v0 = xc[i * D];                // i*D <= 64e6, fits int32
    float v1 = xc[(i + PPI) * D];
    float v2 = xc[(i + 2 * PPI) * D];
    float v3 = xc[(i + 3 * PPI) * D];
    unsafeAtomicAdd(&lsum[c0 * LPAD + dim], v0);
    unsafeAtomicAdd(&lsum[c1 * LPAD + dim], v1);
    unsafeAtomicAdd(&lsum[c2 * LPAD + dim], v2);
    unsafeAtomicAdd(&lsum[c3 * LPAD + dim], v3);
  }
  for (; i < end; i += PPI) {
    int c = y[i];
    float v = xc[i * D];
    unsafeAtomicAdd(&lsum[c * LPAD + dim], v);
  }
  __syncthreads();

  // flush slice to partial[p][c][s*SLICE + d] — plain stores, disjoint regions
  float* dst = partial + (size_t)p * (C * D) + s * SLICE;
  for (int t = threadIdx.x; t < C * SLICE; t += TPB1) {
    int c = t >> 4;   // /SLICE
    int d = t & 15;   // %SLICE
    dst[c * D + d] = lsum[c * LPAD + d];
  }
}

__global__ __launch_bounds__(256) void finalize_kernel(
    const float* __restrict__ partial, const unsigned int* __restrict__ counts,
    const float* __restrict__ centers, const float* __restrict__ counter,
    float* __restrict__ out, int P) {
  constexpr int E4 = C * D / 4;  // 32000 float4 elements
  int e4 = blockIdx.x * 256 + threadIdx.x;
  if (e4 >= E4) return;
  float4 sum = make_float4(0.f, 0.f, 0.f, 0.f);
  const float4* pp = (const float4*)partial;
  for (int p = 0; p < P; ++p) {
    float4 v = pp[(size_t)p * E4 + e4];
    sum.x += v.x; sum.y += v.y; sum.z += v.z; sum.w += v.w;
  }
  int c = (e4 * 4) >> 7;  // element / D
  unsigned int cnt = counts[c];
  float4 cen = ((const float4*)centers)[e4];
  float4 o;
  if (cnt > 0) {
    float inv = 1.f / (float)cnt;
    float k = counter[0];
    float invk1 = 1.f / (k + 1.f);
    o.x = (sum.x * inv + cen.x * k) * invk1;
    o.y = (sum.y * inv + cen.y * k) * invk1;
    o.z = (sum.z * inv + cen.z * k) * invk1;
    o.w = (sum.w * inv + cen.w * k) * invk1;
  } else {
    o = cen;
  }
  ((float4*)out)[e4] = o;
}

extern "C" void kernel_launch(void* const* d_in, const int* in_sizes, int n_in,
                              void* d_out, int out_size, void* d_ws, size_t ws_size,
                              hipStream_t stream) {
  const float* x       = (const float*)d_in[0];
  const int* y         = (const int*)d_in[1];
  const float* centers = (const float*)d_in[2];
  const float* counter = (const float*)d_in[3];
  float* out = (float*)d_out;
  const int N = in_sizes[1];

  unsigned int* counts = (unsigned int*)d_ws;
  float* partial = (float*)((char*)d_ws + 4096);
  const size_t per_buf = (size_t)C * D * sizeof(float);
  size_t maxP = (ws_size > 4096) ? (ws_size - 4096) / per_buf : 0;
  int P = (int)(maxP < 64 ? maxP : 64);
  if (P < 1) P = 1;
  const int chunk = (N + P - 1) / P;

  hipMemsetAsync(d_ws, 0, 4096, stream);  // zero counts region
  counts_kernel<<<dim3(256), dim3(256), 0, stream>>>(y, counts, N);
  partial_sums_kernel<<<dim3(P, NSLICES), dim3(TPB1), 0, stream>>>(
      x, y, partial, N, chunk);
  finalize_kernel<<<dim3((C * D / 4 + 255) / 256), dim3(256), 0, stream>>>(
      partial, counts, centers, counter, out, P);
}

// Round 2
// 469.466 us; speedup vs baseline: 1.2817x; 1.2817x over previous
//
#include <hip/hip_runtime.h>

// RunningCenters via counting sort + register-accumulated segment reduction.
// R1 post-mortem: LDS-atomic slice kernel was latency-serialized (505 GB/s,
// VALU 3.6%). New plan: hist -> scan -> reorder indices by class -> one block
// per class streams its rows with coalesced float2 loads into registers.
// No data atomics, no LDS in the hot loop.

constexpr int C = 1000;
constexpr int D = 128;

// ws layout:
// [0,    4096): counts  u32[C]   (memset to 0 each launch)
// [4096, 12288): offsets u32[C+1]
// [12288,16384): cursors u32[C]
// [16384, ...):  sorted  int[N]  (~2 MB)

__global__ __launch_bounds__(256) void hist_kernel(
    const int* __restrict__ y, unsigned int* __restrict__ counts, int N) {
  __shared__ unsigned int h[C];
  for (int t = threadIdx.x; t < C; t += 256) h[t] = 0u;
  __syncthreads();
  for (int i = blockIdx.x * 256 + threadIdx.x; i < N; i += gridDim.x * 256)
    atomicAdd(&h[y[i]], 1u);
  __syncthreads();
  for (int t = threadIdx.x; t < C; t += 256) {
    unsigned int v = h[t];
    if (v) atomicAdd(&counts[t], v);
  }
}

__global__ __launch_bounds__(1024) void scan_kernel(
    const unsigned int* __restrict__ counts,
    unsigned int* __restrict__ offsets, unsigned int* __restrict__ cursors) {
  __shared__ unsigned int buf[2][1024];
  const int t = threadIdx.x;
  unsigned int v = (t < C) ? counts[t] : 0u;
  buf[0][t] = v;
  __syncthreads();
  int src = 0;
  for (int off = 1; off < 1024; off <<= 1) {
    unsigned int s = buf[src][t];
    if (t >= off) s += buf[src][t - off];
    buf[1 - src][t] = s;
    src = 1 - src;
    __syncthreads();
  }
  if (t < C) {
    unsigned int incl = buf[src][t];   // inclusive scan of counts
    offsets[t + 1] = incl;
    if (t == 0) offsets[0] = 0u;
    cursors[t] = incl - v;             // exclusive offset = running cursor
  }
}

__global__ __launch_bounds__(256) void reorder_kernel(
    const int* __restrict__ y, unsigned int* __restrict__ cursors,
    int* __restrict__ sorted, int N) {
  for (int i = blockIdx.x * 256 + threadIdx.x; i < N; i += gridDim.x * 256) {
    int c = y[i];
    unsigned int pos = atomicAdd(&cursors[c], 1u);
    sorted[pos] = i;
  }
}

// One block (4 waves) per class. Wave w handles points j = begin+w, step 4.
// Lane l accumulates dims [2l, 2l+1] in registers (float2, 512 B/wave-load).
__global__ __launch_bounds__(256) void class_sum_kernel(
    const float* __restrict__ x, const int* __restrict__ sorted,
    const unsigned int* __restrict__ offsets,
    const float* __restrict__ centers, const float* __restrict__ counter,
    float* __restrict__ out) {
  const int c = blockIdx.x;
  const int begin = (int)offsets[c];
  const int end = (int)offsets[c + 1];
  const int wave = threadIdx.x >> 6;
  const int lane = threadIdx.x & 63;

  float sx = 0.f, sy = 0.f;
  int j = begin + wave;
  // unroll 8: 8 independent idx loads, then 8 independent 512B row loads
  for (; j + 28 < end; j += 32) {
    int idx[8];
#pragma unroll
    for (int u = 0; u < 8; ++u) idx[u] = sorted[j + 4 * u];
#pragma unroll
    for (int u = 0; u < 8; ++u) {
      float2 v = ((const float2*)(x + (size_t)idx[u] * D))[lane];
      sx += v.x; sy += v.y;
    }
  }
  for (; j < end; j += 4) {
    float2 v = ((const float2*)(x + (size_t)sorted[j] * D))[lane];
    sx += v.x; sy += v.y;
  }

  __shared__ float red[4][2][64];
  red[wave][0][lane] = sx;
  red[wave][1][lane] = sy;
  __syncthreads();
  if (threadIdx.x < 64) {
    float ax = red[0][0][lane] + red[1][0][lane] + red[2][0][lane] + red[3][0][lane];
    float ay = red[0][1][lane] + red[1][1][lane] + red[2][1][lane] + red[3][1][lane];
    const int cnt = end - begin;
    const float2 cen = ((const float2*)centers)[c * 64 + lane];
    float2 o;
    if (cnt > 0) {
      const float k = counter[0];
      const float inv = 1.f / (float)cnt;
      const float ik = 1.f / (k + 1.f);
      o.x = (ax * inv + cen.x * k) * ik;
      o.y = (ay * inv + cen.y * k) * ik;
    } else {
      o = cen;
    }
    ((float2*)out)[c * 64 + lane] = o;
  }
}

extern "C" void kernel_launch(void* const* d_in, const int* in_sizes, int n_in,
                              void* d_out, int out_size, void* d_ws, size_t ws_size,
                              hipStream_t stream) {
  const float* x       = (const float*)d_in[0];
  const int* y         = (const int*)d_in[1];
  const float* centers = (const float*)d_in[2];
  const float* counter = (const float*)d_in[3];
  float* out = (float*)d_out;
  const int N = in_sizes[1];

  unsigned int* counts  = (unsigned int*)d_ws;
  unsigned int* offsets = (unsigned int*)((char*)d_ws + 4096);
  unsigned int* cursors = (unsigned int*)((char*)d_ws + 12288);
  int* sorted           = (int*)((char*)d_ws + 16384);

  hipMemsetAsync(d_ws, 0, 4096, stream);                       // counts = 0
  hist_kernel<<<dim3(256), dim3(256), 0, stream>>>(y, counts, N);
  scan_kernel<<<dim3(1), dim3(1024), 0, stream>>>(counts, offsets, cursors);
  reorder_kernel<<<dim3(512), dim3(256), 0, stream>>>(y, cursors, sorted, N);
  class_sum_kernel<<<dim3(C), dim3(256), 0, stream>>>(x, sorted, offsets,
                                                      centers, counter, out);
}

// Round 3
// 372.556 us; speedup vs baseline: 1.6151x; 1.2601x over previous
//
#include <hip/hip_runtime.h>

// RunningCenters: deterministic counting sort + register-accumulated gather.
// R2 post-mortem: ~260us of dur is harness reset (1GB ws poison + 256MB x
// restore); controllable chain was ~207us split between contended global
// atomics (reorder) and a latency-chained gather (class_sum).
// R3: two-pass counting sort (LDS hist -> [B][C] matrix -> per-class scan ->
// LDS-cursor scatter) with NO contended global atomics; class_sum stages
// indices in LDS and gathers float4 x 2 rows per wave-load, unroll 4.

constexpr int C = 1000;
constexpr int D = 128;
constexpr int BS = 128;    // sort blocks
constexpr int TS = 512;    // sort threads/block
constexpr int TILE = 2048; // idx staging tile (8 KB LDS)

// ws layout (all regions fully written before read; poison-safe, no memset):
// counts  u32[1024]    @ 0
// offsets u32[1032]    @ 4096
// hist    u32[BS*C]    @ 8192        (500 KB; becomes blockBase in-place)
// sorted  int[N]       @ 8192 + BS*C*4

__global__ __launch_bounds__(TS) void hist_kernel(
    const int* __restrict__ y, unsigned int* __restrict__ hist,
    int N, int chunk) {
  __shared__ unsigned int h[C];
  for (int t = threadIdx.x; t < C; t += TS) h[t] = 0u;
  __syncthreads();
  const int b = blockIdx.x;
  const int beg = b * chunk;
  const int e = min(beg + chunk, N);
  for (int i = beg + threadIdx.x; i < e; i += TS) atomicAdd(&h[y[i]], 1u);
  __syncthreads();
  for (int t = threadIdx.x; t < C; t += TS) hist[b * C + t] = h[t];
}

// one thread per class: scan its column over the BS blocks, in-place replace
// hist[b][c] with the running (within-class, cross-block) exclusive prefix;
// write per-class total to counts[c].
__global__ __launch_bounds__(64) void colscan_kernel(
    unsigned int* __restrict__ hist, unsigned int* __restrict__ counts) {
  const int c = blockIdx.x * 64 + threadIdx.x;
  if (c >= C) return;
  unsigned int run = 0;
  int b = 0;
  for (; b + 3 < BS; b += 4) {
    unsigned int v0 = hist[(b + 0) * C + c];
    unsigned int v1 = hist[(b + 1) * C + c];
    unsigned int v2 = hist[(b + 2) * C + c];
    unsigned int v3 = hist[(b + 3) * C + c];
    hist[(b + 0) * C + c] = run; run += v0;
    hist[(b + 1) * C + c] = run; run += v1;
    hist[(b + 2) * C + c] = run; run += v2;
    hist[(b + 3) * C + c] = run; run += v3;
  }
  for (; b < BS; ++b) {
    unsigned int v = hist[b * C + c];
    hist[b * C + c] = run;
    run += v;
  }
  counts[c] = run;
}

// exclusive scan of counts[0..C) -> offsets[0..C]
__global__ __launch_bounds__(1024) void scan_kernel(
    const unsigned int* __restrict__ counts,
    unsigned int* __restrict__ offsets) {
  __shared__ unsigned int buf[2][1024];
  const int t = threadIdx.x;
  unsigned int v = (t < C) ? counts[t] : 0u;
  buf[0][t] = v;
  __syncthreads();
  int s = 0;
  for (int off = 1; off < 1024; off <<= 1) {
    unsigned int u = buf[s][t];
    if (t >= off) u += buf[s][t - off];
    buf[1 - s][t] = u;
    s = 1 - s;
    __syncthreads();
  }
  if (t < C) {
    unsigned int incl = buf[s][t];
    offsets[t] = incl - v;
    if (t == C - 1) offsets[C] = incl;
  }
}

__global__ __launch_bounds__(TS) void scatter_kernel(
    const int* __restrict__ y, const unsigned int* __restrict__ hist,
    const unsigned int* __restrict__ offsets, int* __restrict__ sorted,
    int N, int chunk) {
  __shared__ unsigned int cur[C];
  const int b = blockIdx.x;
  for (int t = threadIdx.x; t < C; t += TS)
    cur[t] = offsets[t] + hist[b * C + t];
  __syncthreads();
  const int beg = b * chunk;
  const int e = min(beg + chunk, N);
  for (int i = beg + threadIdx.x; i < e; i += TS) {
    int c = y[i];
    unsigned int pos = atomicAdd(&cur[c], 1u);
    sorted[pos] = i;
  }
}

// One block (4 waves) per class. Indices staged in LDS; each wave-load
// covers 2 rows (lane>>5 picks row of pair, lane&31 picks float4 of row).
__global__ __launch_bounds__(256) void class_sum_kernel(
    const float* __restrict__ x, const int* __restrict__ sorted,
    const unsigned int* __restrict__ offsets,
    const float* __restrict__ centers, const float* __restrict__ counter,
    float* __restrict__ out) {
  const int c = blockIdx.x;
  const int begin = (int)offsets[c];
  const int n = (int)offsets[c + 1] - begin;
  const int wave = threadIdx.x >> 6;
  const int lane = threadIdx.x & 63;
  const int half = lane >> 5;   // which row of the pair
  const int d4 = lane & 31;     // which float4 within the row

  __shared__ int idx[TILE];
  __shared__ float4 red[4][64];
  float4 acc = make_float4(0.f, 0.f, 0.f, 0.f);

  for (int t0 = 0; t0 < n; t0 += TILE) {
    const int nt = min(TILE, n - t0);
    __syncthreads();
    for (int t = threadIdx.x; t < nt; t += 256) idx[t] = sorted[begin + t0 + t];
    __syncthreads();
    const int npair = nt >> 1;
    int q = wave;
    for (; q + 12 < npair; q += 16) {  // unroll 4: 4 x 1KB loads in flight
#pragma unroll
      for (int u = 0; u < 4; ++u) {
        const int p = (q + 4 * u) * 2 + half;
        float4 v = ((const float4*)(x + (size_t)idx[p] * D))[d4];
        acc.x += v.x; acc.y += v.y; acc.z += v.z; acc.w += v.w;
      }
    }
    for (; q < npair; q += 4) {
      const int p = q * 2 + half;
      float4 v = ((const float4*)(x + (size_t)idx[p] * D))[d4];
      acc.x += v.x; acc.y += v.y; acc.z += v.z; acc.w += v.w;
    }
    if ((nt & 1) && wave == 0 && half == 0) {  // odd tail point, lanes 0-31
      float4 v = ((const float4*)(x + (size_t)idx[nt - 1] * D))[d4];
      acc.x += v.x; acc.y += v.y; acc.z += v.z; acc.w += v.w;
    }
  }

  red[wave][lane] = acc;
  __syncthreads();
  if (threadIdx.x < 32) {
    const int l = threadIdx.x;
    float4 s = make_float4(0.f, 0.f, 0.f, 0.f);
#pragma unroll
    for (int w = 0; w < 4; ++w) {
      float4 a = red[w][l];
      float4 b = red[w][l + 32];
      s.x += a.x + b.x; s.y += a.y + b.y;
      s.z += a.z + b.z; s.w += a.w + b.w;
    }
    float4 cen = ((const float4*)centers)[c * 32 + l];
    float4 o;
    if (n > 0) {
      const float k = counter[0];
      const float inv = 1.f / (float)n;
      const float ik = 1.f / (k + 1.f);
      o.x = (s.x * inv + cen.x * k) * ik;
      o.y = (s.y * inv + cen.y * k) * ik;
      o.z = (s.z * inv + cen.z * k) * ik;
      o.w = (s.w * inv + cen.w * k) * ik;
    } else {
      o = cen;
    }
    ((float4*)out)[c * 32 + l] = o;
  }
}

extern "C" void kernel_launch(void* const* d_in, const int* in_sizes, int n_in,
                              void* d_out, int out_size, void* d_ws, size_t ws_size,
                              hipStream_t stream) {
  const float* x       = (const float*)d_in[0];
  const int* y         = (const int*)d_in[1];
  const float* centers = (const float*)d_in[2];
  const float* counter = (const float*)d_in[3];
  float* out = (float*)d_out;
  const int N = in_sizes[1];

  unsigned int* counts  = (unsigned int*)d_ws;
  unsigned int* offsets = (unsigned int*)((char*)d_ws + 4096);
  unsigned int* hist    = (unsigned int*)((char*)d_ws + 8192);
  int* sorted           = (int*)((char*)d_ws + 8192 + (size_t)BS * C * 4);

  const int chunk = (N + BS - 1) / BS;

  hist_kernel<<<dim3(BS), dim3(TS), 0, stream>>>(y, hist, N, chunk);
  colscan_kernel<<<dim3(16), dim3(64), 0, stream>>>(hist, counts);
  scan_kernel<<<dim3(1), dim3(1024), 0, stream>>>(counts, offsets);
  scatter_kernel<<<dim3(BS), dim3(TS), 0, stream>>>(y, hist, offsets, sorted,
                                                    N, chunk);
  class_sum_kernel<<<dim3(C), dim3(256), 0, stream>>>(x, sorted, offsets,
                                                      centers, counter, out);
}